// Round 1
// baseline (74.220 us; speedup 1.0000x reference)
//
#include <hip/hip_runtime.h>
#include <cstddef>

namespace {

constexpr int B  = 32;
constexpr int NB = 688;
constexpr int K  = 4;
constexpr int L  = 688;
constexpr int S  = 688;
constexpr int V  = 50;
constexpr int LS = L + S;            // 1376
constexpr int ROWS  = B * NB;        // 22016 pointer / contrastive rows
constexpr int TROWS = B * S;         // 22016 tag rows
constexpr float TINV = 10.0f;        // 1 / TEMP

// role block counts
constexpr int NPTR = 1024, NROW = 1024, NCOL = 1024, NTAG = 256, NEMP = 8;
constexpr int NBLK = NPTR + NROW + NCOL + NTAG + NEMP;   // 3336

// ws layout (doubles)
constexpr int PT0 = 0;      // ptr total        [1024]
constexpr int PH0 = 1024;   // ptr has-count    [1024]
constexpr int RS0 = 2048;   // row sum          [1024]
constexpr int RV0 = 3072;   // row vb-count     [1024]
constexpr int CS0 = 4096;   // col sum          [1024]
constexpr int CV0 = 5120;   // col vb-count     [1024]
constexpr int TS0 = 6144;   // tag sum          [256]
constexpr int TC0 = 6400;   // tag valid count  [256]
constexpr int ES0 = 6656;   // empty partial    [8]

__device__ __forceinline__ float wred_max(float v) {
#pragma unroll
  for (int o = 32; o > 0; o >>= 1) v = fmaxf(v, __shfl_xor(v, o));
  return v;
}
__device__ __forceinline__ float wred_sum(float v) {
#pragma unroll
  for (int o = 32; o > 0; o >>= 1) v += __shfl_xor(v, o);
  return v;
}

// ---------------- pointer loss row: (b, nb) ----------------
__device__ __forceinline__ void ptr_row(int r, int lane,
    const float* __restrict__ plog, const int* __restrict__ box,
    const int* __restrict__ dmask, double& a0, double& a1)
{
  const float* pl = plog + (size_t)r * S;
  const float4* pl4 = reinterpret_cast<const float4*>(pl);
  float x[12];
#pragma unroll
  for (int i = 0; i < 3; ++i) {
    int j4 = lane + i * 64;
    if (j4 < S / 4) {
      float4 v = pl4[j4];
      x[4*i+0] = v.x * TINV; x[4*i+1] = v.y * TINV;
      x[4*i+2] = v.z * TINV; x[4*i+3] = v.w * TINV;
    } else {
      x[4*i+0] = x[4*i+1] = x[4*i+2] = x[4*i+3] = -INFINITY;
    }
  }
  float m = -INFINITY;
#pragma unroll
  for (int i = 0; i < 12; ++i) m = fmaxf(m, x[i]);
  m = wred_max(m);
  float z = 0.f;
#pragma unroll
  for (int i = 0; i < 12; ++i) z += __expf(x[i] - m);
  z = wred_sum(z);
  float lse = m + __logf(z);

  float g = 0.f, vld = 0.f;
  if (lane < K) {
    int idx = box[(size_t)r * K + lane];
    if (idx != -1) {
      vld = 1.f;
      int b = r / NB;
      int vp = dmask[(size_t)b * LS + L + idx];
      float sv = pl[idx] * TINV;
      g = vp ? (sv - lse) : -INFINITY;
    }
  }
  float gs  = wred_sum(g);
  float cnt = wred_sum(vld);
  if (cnt > 0.f) {
    float per = -(gs / fmaxf(cnt, 1.f));
    a0 += (double)per;
    a1 += 1.0;
  }
}

// ---------------- contrastive loss row ----------------
__device__ __forceinline__ void con_row(int r, int lane,
    const float* __restrict__ sim, const float* __restrict__ coef,
    double& a0, double& a1)
{
  const float4* sp4 = reinterpret_cast<const float4*>(sim  + (size_t)r * S);
  const float4* cp4 = reinterpret_cast<const float4*>(coef + (size_t)r * S);
  float x[12];
#pragma unroll
  for (int i = 0; i < 3; ++i) {
    int j4 = lane + i * 64;
    if (j4 < S / 4) {
      float4 v = sp4[j4];
      x[4*i+0] = v.x * TINV; x[4*i+1] = v.y * TINV;
      x[4*i+2] = v.z * TINV; x[4*i+3] = v.w * TINV;
    } else {
      x[4*i+0] = x[4*i+1] = x[4*i+2] = x[4*i+3] = -INFINITY;
    }
  }
  float m = -INFINITY;
#pragma unroll
  for (int i = 0; i < 12; ++i) m = fmaxf(m, x[i]);
  m = wred_max(m);
  float e[12];
  float z = 0.f;
#pragma unroll
  for (int i = 0; i < 12; ++i) { e[i] = __expf(x[i] - m); z += e[i]; }
  z = wred_sum(z);
  float zinv = 1.0f / z;

  float wsum = 0.f, csum = 0.f, anyv = 0.f;
#pragma unroll
  for (int i = 0; i < 3; ++i) {
    int j4 = lane + i * 64;
    if (j4 < S / 4) {
      float4 c = cp4[j4];
      float cc[4] = {c.x, c.y, c.z, c.w};
#pragma unroll
      for (int l = 0; l < 4; ++l) {
        float p  = e[4*i+l] * zinv;
        float lp = __logf(p + 1e-8f);        // matches log(softmax + 1e-8)
        csum += cc[l];
        if (cc[l] >= 0.f) { wsum += cc[l] * lp; anyv = 1.f; }
      }
    }
  }
  wsum = wred_sum(wsum); csum = wred_sum(csum); anyv = wred_sum(anyv);
  if (anyv > 0.f) {
    float box = -(wsum / (csum + 1e-8f));
    a0 += (double)box;
    a1 += 1.0;
  }
}

// ---------------- tag loss row ----------------
__device__ __forceinline__ void tag_row(int row, int lane,
    const float* __restrict__ tl_base, const int* __restrict__ tgt,
    double& a0, double& a1)
{
  const float* tl = tl_base + (size_t)row * V;
  float xv = (lane < V) ? tl[lane] : -INFINITY;
  float m  = wred_max(xv);
  float ev = (lane < V) ? __expf(xv - m) : 0.f;
  float z  = wred_sum(ev);
  float sx = (lane < V) ? xv : 0.f;
  float sumx = wred_sum(sx);
  float lse = m + __logf(z);
  int t = tgt[row];
  float xt = __shfl(xv, t);          // t in [0, 50)
  if (t != 0) {                      // PAD == 0
    // per = 0.9*(lse - x_t) + 0.1*(lse - mean_x)
    float per = lse - 0.9f * xt - 0.1f * (sumx * (1.0f / (float)V));
    a0 += (double)per;
    a1 += 1.0;
  }
}

// ---------------- empty BCE row (one batch b per wave) ----------------
__device__ __forceinline__ void empty_row(int b, int lane,
    const float* __restrict__ elog, const int* __restrict__ dmask,
    const int* __restrict__ emask, double& a0)
{
  const float* el = elog + (size_t)b * S;
  const int* dm = dmask + (size_t)b * LS + L;
  const int* em = emask + (size_t)b * LS + L;
  float bs = 0.f, bc = 0.f;
  for (int j = lane; j < S; j += 64) {
    float xv = el[j];
    int d = dm[j], e = em[j];
    int o = d | e;
    float tt = (float)e;
    float bce = fmaxf(xv, 0.f) - xv * tt + log1pf(__expf(-fabsf(xv)));
    if (o) { bs += bce; bc += 1.f; }
  }
  bs = wred_sum(bs);
  bc = wred_sum(bc);
  a0 += (double)(bs / (bc + 1e-8f));
}

__global__ __launch_bounds__(256) void fused_loss(
    const float* __restrict__ tag_logits, const int* __restrict__ tag_targets,
    const float* __restrict__ plog, const int* __restrict__ box,
    const int* __restrict__ dmask, const int* __restrict__ emask,
    const float* __restrict__ elog,
    const float* __restrict__ rsim, const float* __restrict__ csim,
    const float* __restrict__ rcoef, const float* __restrict__ ccoef,
    double* __restrict__ ws)
{
  const int tid  = threadIdx.x;
  const int lane = tid & 63;
  const int wave = tid >> 6;
  const int bid  = blockIdx.x;

  double a0 = 0.0, a1 = 0.0;
  int role, rb;
  if      (bid < NPTR)                      { role = 0; rb = bid; }
  else if (bid < NPTR + NROW)               { role = 1; rb = bid - NPTR; }
  else if (bid < NPTR + NROW + NCOL)        { role = 2; rb = bid - (NPTR + NROW); }
  else if (bid < NPTR + NROW + NCOL + NTAG) { role = 3; rb = bid - (NPTR + NROW + NCOL); }
  else                                      { role = 4; rb = bid - (NPTR + NROW + NCOL + NTAG); }

  if (role == 0) {
    const int wid = rb * 4 + wave, W = NPTR * 4;
    for (int r = wid; r < ROWS; r += W) ptr_row(r, lane, plog, box, dmask, a0, a1);
  } else if (role == 1) {
    const int wid = rb * 4 + wave, W = NROW * 4;
    for (int r = wid; r < ROWS; r += W) con_row(r, lane, rsim, rcoef, a0, a1);
  } else if (role == 2) {
    const int wid = rb * 4 + wave, W = NCOL * 4;
    for (int r = wid; r < ROWS; r += W) con_row(r, lane, csim, ccoef, a0, a1);
  } else if (role == 3) {
    const int wid = rb * 4 + wave, W = NTAG * 4;
    for (int r = wid; r < TROWS; r += W) tag_row(r, lane, tag_logits, tag_targets, a0, a1);
  } else {
    const int b = rb * 4 + wave;   // 8 blocks * 4 waves = 32 batches
    empty_row(b, lane, elog, dmask, emask, a0);
  }

  __shared__ double s0[4], s1[4];
  if (lane == 0) { s0[wave] = a0; s1[wave] = a1; }
  __syncthreads();
  if (tid == 0) {
    double t0 = s0[0] + s0[1] + s0[2] + s0[3];
    double t1 = s1[0] + s1[1] + s1[2] + s1[3];
    switch (role) {
      case 0:  ws[PT0 + rb] = t0; ws[PH0 + rb] = t1; break;
      case 1:  ws[RS0 + rb] = t0; ws[RV0 + rb] = t1; break;
      case 2:  ws[CS0 + rb] = t0; ws[CV0 + rb] = t1; break;
      case 3:  ws[TS0 + rb] = t0; ws[TC0 + rb] = t1; break;
      default: ws[ES0 + rb] = t0; break;
    }
  }
}

__global__ void combine_kernel(const double* __restrict__ ws,
                               float* __restrict__ out)
{
  const int lane = threadIdx.x;   // blockDim.x == 64
  double pt = 0, ph = 0, rs = 0, rv = 0, cs = 0, cv = 0, ts = 0, tc = 0, es = 0;
  for (int i = lane; i < 1024; i += 64) {
    pt += ws[PT0 + i]; ph += ws[PH0 + i];
    rs += ws[RS0 + i]; rv += ws[RV0 + i];
    cs += ws[CS0 + i]; cv += ws[CV0 + i];
  }
  for (int i = lane; i < 256; i += 64) { ts += ws[TS0 + i]; tc += ws[TC0 + i]; }
  if (lane < 8) es = ws[ES0 + lane];
#pragma unroll
  for (int o = 32; o > 0; o >>= 1) {
    pt += __shfl_xor(pt, o); ph += __shfl_xor(ph, o);
    rs += __shfl_xor(rs, o); rv += __shfl_xor(rv, o);
    cs += __shfl_xor(cs, o); cv += __shfl_xor(cv, o);
    ts += __shfl_xor(ts, o); tc += __shfl_xor(tc, o);
    es += __shfl_xor(es, o);
  }
  if (lane == 0) {
    float cls  = (float)(ts / tc);
    float ptr  = (float)(pt / (ph + 1e-6));
    float emp  = (float)(es / (double)B);
    float row  = (float)(rs / (rv + 1e-8));
    float col  = (float)(cs / (cv + 1e-8));
    float total = cls + ptr + emp + 0.5f * row + 0.5f * col;
    out[0] = total; out[1] = cls; out[2] = ptr;
    out[3] = emp;   out[4] = row; out[5] = col;
  }
}

} // anonymous namespace

extern "C" void kernel_launch(void* const* d_in, const int* in_sizes, int n_in,
                              void* d_out, int out_size, void* d_ws, size_t ws_size,
                              hipStream_t stream)
{
  const float* tag_logits  = (const float*)d_in[0];
  const int*   tag_targets = (const int*)  d_in[1];
  const float* plog        = (const float*)d_in[2];
  const int*   box         = (const int*)  d_in[3];
  const int*   dmask       = (const int*)  d_in[4];
  const int*   emask       = (const int*)  d_in[5];
  const float* elog        = (const float*)d_in[6];
  const float* rsim        = (const float*)d_in[7];
  const float* csim        = (const float*)d_in[8];
  const float* rcoef       = (const float*)d_in[9];
  const float* ccoef       = (const float*)d_in[10];

  double* ws = (double*)d_ws;
  float* out = (float*)d_out;

  fused_loss<<<NBLK, 256, 0, stream>>>(tag_logits, tag_targets, plog, box,
                                       dmask, emask, elog, rsim, csim,
                                       rcoef, ccoef, ws);
  combine_kernel<<<1, 64, 0, stream>>>(ws, out);
}